// Round 14
// baseline (738.433 us; speedup 1.0000x reference)
//
#include <hip/hip_runtime.h>
#include <math.h>

#define N_NODES 50000
#define MPAD    50048                              // 64 * 782, padded row count
#define N_EDGES 800000
#define FDIM    128
#define NGRAPH  128

// deterministic multi-split CSR build
#define NCB   196                                  // coarse buckets (dst>>8, 256 nodes each)
#define CBN   256                                  // nodes per coarse bucket
#define ABLK  256                                  // histogram/scatter blocks
#define EPB   (N_EDGES / ABLK)                     // 3125 edges per block (exact)
#define CVT_BLOCKS ((MPAD * FDIM / 4 + 255) / 256) // 6256 convert blocks

typedef __attribute__((ext_vector_type(8))) short short8;   // 8 bf16 = 4 VGPRs
typedef __attribute__((ext_vector_type(4))) float f32x4;
typedef unsigned int u32;

__device__ __forceinline__ unsigned short f2bf(float f) {   // RNE
    unsigned int u = __float_as_uint(f);
    return (unsigned short)((u + 0x7FFFu + ((u >> 16) & 1u)) >> 16);
}
__device__ __forceinline__ float bfhi(unsigned int u) { return __uint_as_float(u & 0xFFFF0000u); }
__device__ __forceinline__ float bflo(unsigned int u) { return __uint_as_float(u << 16); }

// ---------------- pre: x->bf16 convert (blocks [0,CVT)) + edge histogram (rest) ----------
__global__ __launch_bounds__(256) void pre_kernel(const float* __restrict__ x,
                                                  unsigned short* __restrict__ xb,
                                                  const int* __restrict__ edges,
                                                  int* __restrict__ g_hist) {
    __shared__ int hist[NCB];
    int t = threadIdx.x;
    if (blockIdx.x < CVT_BLOCKS) {
        int i = blockIdx.x * 256 + t;
        if (i >= MPAD * FDIM / 4) return;
        int base = i * 4;
        uint2 o;
        if (base < N_NODES * FDIM) {
            float4 v = *(const float4*)&x[base];
            o.x = (u32)f2bf(v.x) | ((u32)f2bf(v.y) << 16);
            o.y = (u32)f2bf(v.z) | ((u32)f2bf(v.w) << 16);
        } else { o.x = 0u; o.y = 0u; }
        *(uint2*)&xb[base] = o;
    } else {
        int blk = blockIdx.x - CVT_BLOCKS;
        if (t < NCB) hist[t] = 0;
        __syncthreads();
        int beg = blk * EPB, end = beg + EPB;
        for (int i = beg + t; i < end; i += 256) {
            int2 ed = ((const int2*)edges)[i];
            atomicAdd(&hist[ed.y >> 8], 1);
        }
        __syncthreads();
        if (t < NCB) g_hist[blk * NCB + t] = hist[t];   // [b][t]: scan reads coalesced
    }
}

// ---------------- scan: per-(bucket,block) local bases + bucket bases ----------------
__global__ __launch_bounds__(256) void scan_kernel(const int* __restrict__ g_hist,
                                                   int* __restrict__ g_base,
                                                   int* __restrict__ cbbase,
                                                   int* __restrict__ cbtotal,
                                                   int* __restrict__ row_ptr) {
    __shared__ int tot[NCB];
    int t = threadIdx.x;
    if (t < NCB) {
        int run = 0;
        for (int b = 0; b < ABLK; ++b) {          // coalesced over t each iter
            int v = g_hist[b * NCB + t];
            g_base[b * NCB + t] = run;
            run += v;
        }
        tot[t] = run;
    }
    __syncthreads();
    if (t == 0) {
        int run = 0;
        for (int c = 0; c < NCB; ++c) { cbbase[c] = run; cbtotal[c] = tot[c]; run += tot[c]; }
        row_ptr[N_NODES] = N_EDGES;
    }
}

// ---------------- A2: deterministic scatter into coarse buckets ----------------
__global__ __launch_bounds__(256) void scatter_kernel(const int* __restrict__ edges,
                                                      const int* __restrict__ g_base,
                                                      const int* __restrict__ cbbase,
                                                      u32* __restrict__ coarse) {
    __shared__ int cur[NCB];
    int t = threadIdx.x, blk = blockIdx.x;
    if (t < NCB) cur[t] = g_base[blk * NCB + t] + cbbase[t];
    __syncthreads();
    int beg = blk * EPB, end = beg + EPB;
    for (int i = beg + t; i < end; i += 256) {
        int2 ed = ((const int2*)edges)[i];   // x=src, y=dst
        int cb = ed.y >> 8;
        int pos = atomicAdd(&cur[cb], 1);
        coarse[pos] = ((u32)(ed.y & 255) << 16) | (u32)ed.x;
    }
}

// ---- B: per-coarse-bucket LDS counting sort -> csr_srcd (dloc64<<16|src), row_ptr, invdeg ----
__global__ __launch_bounds__(256) void csr_kernel(const int* __restrict__ cbbase,
                                                  const int* __restrict__ cbtotal,
                                                  const u32* __restrict__ coarse,
                                                  u32* __restrict__ csr_srcd,
                                                  int* __restrict__ row_ptr,
                                                  float* __restrict__ invdeg) {
    __shared__ int cnt_l[CBN];
    __shared__ int off_l[CBN];
    int cb = blockIdx.x, t = threadIdx.x;
    int n = cbtotal[cb], base = cbbase[cb];
    cnt_l[t] = 0;
    __syncthreads();
    const u32* ce = coarse + base;
    for (int i = t; i < n; i += 256) atomicAdd(&cnt_l[ce[i] >> 16], 1);
    __syncthreads();
    if (t == 0) {
        int run = base;
        for (int i = 0; i < CBN; ++i) { off_l[i] = run; run += cnt_l[i]; }
    }
    __syncthreads();
    int node0 = cb * CBN;
    if (node0 + t < N_NODES) {
        row_ptr[node0 + t] = off_l[t];
        invdeg[node0 + t] = 1.0f / (float)max(cnt_l[t], 1);
    }
    __syncthreads();   // row_ptr snapshot before cursors move
    for (int i = t; i < n; i += 256) {
        u32 ev = ce[i];
        int pos = atomicAdd(&off_l[ev >> 16], 1);
        csr_srcd[pos] = (ev & 0xFFFFu) | ((((ev >> 16) & 63u)) << 16);  // dloc64<<16 | src
    }
}

// -------- weights -> bf16 transposed+concat; also zero gsum + per-graph invcnt --------
struct WPtrs { const float* wl[5]; const float* wr[5]; };
__global__ void convert_w_kernel(WPtrs wp, unsigned short* __restrict__ wcat,
                                 const int* __restrict__ batch,
                                 float* __restrict__ gsum,
                                 float* __restrict__ invcnt) {
    int t = blockIdx.x * blockDim.x + threadIdx.x;   // 5*128*256 = 163840
    if (t < NGRAPH * FDIM) gsum[t] = 0.0f;           // fold gsum zeroing
    if (t < NGRAPH) {                                // fold per-graph 1/count
        int g = t;
        int lo = 0, hi = N_NODES;
        while (lo < hi) { int mid = (lo + hi) >> 1; if (batch[mid] < g) lo = mid + 1; else hi = mid; }
        int beg = lo;
        hi = N_NODES;
        while (lo < hi) { int mid = (lo + hi) >> 1; if (batch[mid] < g + 1) lo = mid + 1; else hi = mid; }
        invcnt[g] = 1.0f / (float)max(lo - beg, 1);
    }
    if (t >= 5 * 128 * 256) return;
    int l = t >> 15;
    int rem = t & 32767;
    int k = rem >> 7;        // 0..255
    int n = rem & 127;       // coalesced read over n
    const float* W = (k < 128) ? wp.wl[l] : wp.wr[l];
    float v = W[(k & 127) * 128 + n];
    wcat[((size_t)l << 15) + n * 256 + k] = f2bf(v);
}

// ---------------- fused SAGE layer: edge-balanced gather -> LDS fp32 acc -> MFMA --------
// 512 thr (8 waves), 64 rows/block. Gather: fixed 16-edge chunks per slot
// (removes the Poisson-degree wave-divergence waste that R9/R10/R11 all shared);
// one coalesced idx load + shfl broadcast + 8 rows in flight; run-boundary
// flush into accf[64][132] fp32 (pad 4 -> <=4-way banks) via LDS atomics.
// pool_batch != nullptr (layer 5): fold graph-sum pool into epilogue (R13).
__global__ __launch_bounds__(512) void sage_fused_kernel(
        const unsigned short* __restrict__ h,    // [MPAD][128] bf16
        const int* __restrict__ row_ptr,
        const u32* __restrict__ csr_srcd,        // (dloc64<<16)|src, dst-sorted
        const float* __restrict__ invdeg,
        const unsigned short* __restrict__ Wcat, // [128 n][256 k] bf16
        const float* __restrict__ bias,
        unsigned short* __restrict__ out,
        const int* __restrict__ pool_batch,      // null for layers 1-4
        float* __restrict__ gsum) {
    __shared__ float accf[64 * 132];
    __shared__ unsigned short As[64][136];
    int t = threadIdx.x;
    int node0 = blockIdx.x * 64;

    // ---- phase 0: zero the fp32 accumulator ----
    for (int i = t; i < 64 * 132; i += 512) accf[i] = 0.0f;
    __syncthreads();

    // ---- phase 1: edge-balanced gather ----
    {
        int slot = t >> 4;                  // 0..31
        int lane = t & 15;
        int c = lane * 8;                   // 8 feats (16 B) per lane
        int wbase = ((t >> 4) & 3) * 16;    // slot's base lane within the wave
        int beg = row_ptr[node0];
        int end = row_ptr[min(node0 + 64, N_NODES)];
        int nchunks = (end - beg + 15) >> 4;
        for (int ck = slot; ck < nchunks; ck += 32) {
            int e0 = beg + ck * 16;
            int cnt = min(16, end - e0);    // slot-uniform
            u32 ev = (lane < cnt) ? csr_srcd[e0 + lane] : 0xFFFF0000u;
            u32 evj[8]; uint4 v[8];
            // batch 1: edges 0..7 (loads issued back-to-back)
            #pragma unroll
            for (int j = 0; j < 8; ++j) {
                evj[j] = (u32)__shfl((int)ev, wbase + j, 64);
                if (j < cnt) v[j] = *(const uint4*)&h[(size_t)(evj[j] & 0xFFFFu) * FDIM + c];
            }
            int rund = (int)(evj[0] >> 16);
            float r[8] = {0.f, 0.f, 0.f, 0.f, 0.f, 0.f, 0.f, 0.f};
            #pragma unroll
            for (int j = 0; j < 8; ++j) {
                if (j < cnt) {
                    int d = (int)(evj[j] >> 16);
                    if (d != rund) {
                        float* ap = &accf[rund * 132 + c];
                        #pragma unroll
                        for (int k = 0; k < 8; ++k) { atomicAdd(&ap[k], r[k]); r[k] = 0.f; }
                        rund = d;
                    }
                    r[0] += bflo(v[j].x); r[1] += bfhi(v[j].x);
                    r[2] += bflo(v[j].y); r[3] += bfhi(v[j].y);
                    r[4] += bflo(v[j].z); r[5] += bfhi(v[j].z);
                    r[6] += bflo(v[j].w); r[7] += bfhi(v[j].w);
                }
            }
            // batch 2: edges 8..15
            #pragma unroll
            for (int j = 0; j < 8; ++j) {
                evj[j] = (u32)__shfl((int)ev, wbase + 8 + j, 64);
                if (8 + j < cnt) v[j] = *(const uint4*)&h[(size_t)(evj[j] & 0xFFFFu) * FDIM + c];
            }
            #pragma unroll
            for (int j = 0; j < 8; ++j) {
                if (8 + j < cnt) {
                    int d = (int)(evj[j] >> 16);
                    if (d != rund) {
                        float* ap = &accf[rund * 132 + c];
                        #pragma unroll
                        for (int k = 0; k < 8; ++k) { atomicAdd(&ap[k], r[k]); r[k] = 0.f; }
                        rund = d;
                    }
                    r[0] += bflo(v[j].x); r[1] += bfhi(v[j].x);
                    r[2] += bflo(v[j].y); r[3] += bfhi(v[j].y);
                    r[4] += bflo(v[j].z); r[5] += bfhi(v[j].z);
                    r[6] += bflo(v[j].w); r[7] += bfhi(v[j].w);
                }
            }
            if (cnt > 0) {
                float* ap = &accf[rund * 132 + c];
                #pragma unroll
                for (int k = 0; k < 8; ++k) atomicAdd(&ap[k], r[k]);
            }
        }
    }
    __syncthreads();

    // ---- phase 1b: accf * invdeg -> bf16 As ----
    {
        int row = t >> 3;                  // 0..63
        int k0 = (t & 7) * 16;
        int node = node0 + row;
        float inv = (node < N_NODES) ? invdeg[node] : 1.0f;
        #pragma unroll
        for (int k = 0; k < 16; k += 2) {
            float a0 = accf[row * 132 + k0 + k] * inv;
            float a1 = accf[row * 132 + k0 + k + 1] * inv;
            *(u32*)&As[row][k0 + k] = (u32)f2bf(a0) | ((u32)f2bf(a1) << 16);
        }
    }
    __syncthreads();

    // ---- phase 2: MFMA (8 waves; pair (stripe,half) covers 16 rows x 64 cols) ----
    int wave = t >> 6;
    int lane = t & 63;
    int l15 = lane & 15;
    int q = lane >> 4;
    int stripe = wave >> 1;              // 0..3 -> 16-row stripe
    int half = wave & 1;                 // 0..1 -> col-blocks half*4 .. half*4+3
    int row_base = node0 + stripe * 16;

    f32x4 acc[4];
    #pragma unroll
    for (int i = 0; i < 4; ++i) acc[i] = (f32x4){0.f, 0.f, 0.f, 0.f};

    // p=0: A = agg tile (LDS), Wl (k<128)
    {
        const unsigned short* Wb = Wcat + (size_t)(half * 64 + l15) * 256 + q * 8;
        #pragma unroll
        for (int k0 = 0; k0 < 128; k0 += 32) {
            short8 a = *(const short8*)&As[stripe * 16 + l15][q * 8 + k0];
            #pragma unroll
            for (int j = 0; j < 4; ++j) {
                short8 b = *(const short8*)(Wb + (size_t)j * 16 * 256 + k0);
                acc[j] = __builtin_amdgcn_mfma_f32_16x16x32_bf16(a, b, acc[j], 0, 0, 0);
            }
        }
    }
    // p=1: A = h (global bf16), Wr (k>=128)
    {
        const unsigned short* Ab = h + (size_t)(row_base + l15) * FDIM + q * 8;
        const unsigned short* Wb = Wcat + (size_t)(half * 64 + l15) * 256 + 128 + q * 8;
        #pragma unroll
        for (int k0 = 0; k0 < 128; k0 += 32) {
            short8 a = *(const short8*)(Ab + k0);
            #pragma unroll
            for (int j = 0; j < 4; ++j) {
                short8 b = *(const short8*)(Wb + (size_t)j * 16 * 256 + k0);
                acc[j] = __builtin_amdgcn_mfma_f32_16x16x32_bf16(a, b, acc[j], 0, 0, 0);
            }
        }
    }

    if (pool_batch == nullptr) {
        // epilogue: bias + relu + bf16 store
        #pragma unroll
        for (int j = 0; j < 4; ++j) {
            int col = (half * 4 + j) * 16 + l15;
            float bv = bias[col];
            #pragma unroll
            for (int r = 0; r < 4; ++r) {
                int row = row_base + q * 4 + r;
                float v = fmaxf(acc[j][r] + bv, 0.f);
                out[(size_t)row * FDIM + col] = f2bf(v);
            }
        }
    } else {
        // layer-5 epilogue: stage relu tile in LDS, in-block sorted-batch pool.
        __syncthreads();                 // all waves done READING As (p=0)
        #pragma unroll
        for (int j = 0; j < 4; ++j) {
            int col = (half * 4 + j) * 16 + l15;
            float bv = bias[col];
            #pragma unroll
            for (int r = 0; r < 4; ++r) {
                int rl = stripe * 16 + q * 4 + r;
                As[rl][col] = f2bf(fmaxf(acc[j][r] + bv, 0.f));
            }
        }
        __syncthreads();
        if (t < FDIM) {
            int f = t;
            int nmax = min(64, N_NODES - node0);
            float a = 0.0f;
            int cur = pool_batch[node0];
            for (int r = 0; r < nmax; ++r) {
                int b = pool_batch[node0 + r];     // broadcast read
                if (b != cur) {
                    atomicAdd(&gsum[cur * FDIM + f], a);
                    a = 0.0f;
                    cur = b;
                }
                a += bflo((u32)As[r][f]);
            }
            atomicAdd(&gsum[cur * FDIM + f], a);
        }
    }
}

// ---------------- final MLP head (fp32): sigmoid(relu((gsum/cnt)@Wf1+bf1)@Wf2+bf2) -------
__global__ void mlp_kernel(const float* __restrict__ gsum,
                           const float* __restrict__ invcnt,
                           const float* __restrict__ Wf1, const float* __restrict__ bf1,
                           const float* __restrict__ Wf2, const float* __restrict__ bf2,
                           float* __restrict__ out) {
    int gg = blockIdx.x;
    int j = threadIdx.x;   // 128
    __shared__ float row[128];
    __shared__ float red[128];
    row[j] = gsum[gg * 128 + j] * invcnt[gg];
    __syncthreads();
    float acc = bf1[j];
    for (int k = 0; k < 128; ++k) acc = fmaf(row[k], Wf1[k * 128 + j], acc);
    float v = fmaxf(acc, 0.0f);
    red[j] = v * Wf2[j];
    __syncthreads();
    for (int off = 64; off > 0; off >>= 1) {
        if (j < off) red[j] += red[j + off];
        __syncthreads();
    }
    if (j == 0) out[gg] = 1.0f / (1.0f + expf(-(red[0] + bf2[0])));
}

extern "C" void kernel_launch(void* const* d_in, const int* in_sizes, int n_in,
                              void* d_out, int out_size, void* d_ws, size_t ws_size,
                              hipStream_t stream) {
    const float* x      = (const float*)d_in[0];
    const int*   edges  = (const int*)d_in[1];
    const int*   batch  = (const int*)d_in[2];
    WPtrs wp;
    const float* bs[5];
    for (int l = 0; l < 5; ++l) {
        wp.wl[l] = (const float*)d_in[3 + 3 * l];
        wp.wr[l] = (const float*)d_in[4 + 3 * l];
        bs[l]    = (const float*)d_in[5 + 3 * l];
    }
    const float* Wf1 = (const float*)d_in[18];
    const float* bf1 = (const float*)d_in[19];
    const float* Wf2 = (const float*)d_in[20];
    const float* bf2 = (const float*)d_in[21];
    float* out = (float*)d_out;

    // workspace carve-up (256B aligned)
    char* ws = (char*)d_ws;
    auto alloc = [&](size_t bytes) { void* p = (void*)ws; ws += (bytes + 255) & ~(size_t)255; return p; };
    unsigned short* xb   = (unsigned short*)alloc((size_t)MPAD * FDIM * 2);
    unsigned short* hA   = (unsigned short*)alloc((size_t)MPAD * FDIM * 2);
    unsigned short* hB   = (unsigned short*)alloc((size_t)MPAD * FDIM * 2);
    unsigned short* wcat = (unsigned short*)alloc((size_t)5 * 128 * 256 * 2);
    u32*   coarse   = (u32*)alloc((size_t)N_EDGES * 4);
    int*   g_hist   = (int*)alloc((size_t)NCB * ABLK * 4);
    int*   g_base   = (int*)alloc((size_t)NCB * ABLK * 4);
    int*   cbbase   = (int*)alloc((size_t)NCB * 4);
    int*   cbtotal  = (int*)alloc((size_t)NCB * 4);
    int*   row_ptr  = (int*)alloc((size_t)(N_NODES + 1) * 4);
    u32*   csr_srcd = (u32*)alloc((size_t)N_EDGES * 4);
    float* invdeg   = (float*)alloc((size_t)N_NODES * 4);
    float* gsum     = (float*)alloc((size_t)NGRAPH * FDIM * 4);
    float* invcnt   = (float*)alloc((size_t)NGRAPH * 4);
    (void)ws_size; (void)in_sizes; (void)n_in; (void)out_size;

    // ---- conversions + CSR build (deterministic multi-split) ----
    pre_kernel<<<CVT_BLOCKS + ABLK, 256, 0, stream>>>(x, xb, edges, g_hist);
    convert_w_kernel<<<(5 * 128 * 256 + 255) / 256, 256, 0, stream>>>(wp, wcat, batch, gsum, invcnt);
    scan_kernel<<<1, 256, 0, stream>>>(g_hist, g_base, cbbase, cbtotal, row_ptr);
    scatter_kernel<<<ABLK, 256, 0, stream>>>(edges, g_base, cbbase, coarse);
    csr_kernel<<<NCB, 256, 0, stream>>>(cbbase, cbtotal, coarse, csr_srcd, row_ptr, invdeg);

    // ---- 5 fused SAGE layers; layer 5 folds the graph mean-pool ----
    const unsigned short* hcur = xb;
    unsigned short* bufs[2] = {hA, hB};
    for (int l = 0; l < 5; ++l) {
        unsigned short* hnext = bufs[l & 1];
        const int* pb = (l == 4) ? batch : nullptr;
        sage_fused_kernel<<<MPAD / 64, 512, 0, stream>>>(
            hcur, row_ptr, csr_srcd, invdeg, wcat + ((size_t)l << 15), bs[l], hnext, pb, gsum);
        hcur = hnext;
    }

    // ---- head ----
    mlp_kernel<<<NGRAPH, 128, 0, stream>>>(gsum, invcnt, Wf1, bf1, Wf2, bf2, out);
}

// Round 15
// 468.504 us; speedup vs baseline: 1.5762x; 1.5762x over previous
//
#include <hip/hip_runtime.h>
#include <math.h>

#define N_NODES 50000
#define MPAD    50048                              // 64 * 782, padded row count
#define N_EDGES 800000
#define FDIM    128
#define NGRAPH  128

// deterministic multi-split CSR build
#define NCB   196                                  // coarse buckets (dst>>8, 256 nodes each)
#define CBN   256                                  // nodes per coarse bucket
#define ABLK  256                                  // histogram/scatter blocks
#define EPB   (N_EDGES / ABLK)                     // 3125 edges per block (exact)
#define CVT_BLOCKS ((MPAD * FDIM / 4 + 255) / 256) // 6256 convert blocks

typedef __attribute__((ext_vector_type(8))) short short8;   // 8 bf16 = 4 VGPRs
typedef __attribute__((ext_vector_type(4))) float f32x4;
typedef unsigned int u32;

__device__ __forceinline__ unsigned short f2bf(float f) {   // RNE
    unsigned int u = __float_as_uint(f);
    return (unsigned short)((u + 0x7FFFu + ((u >> 16) & 1u)) >> 16);
}
__device__ __forceinline__ float bfhi(unsigned int u) { return __uint_as_float(u & 0xFFFF0000u); }
__device__ __forceinline__ float bflo(unsigned int u) { return __uint_as_float(u << 16); }

// ---------------- pre: x->bf16 convert (blocks [0,CVT)) + edge histogram (rest) ----------
__global__ __launch_bounds__(256) void pre_kernel(const float* __restrict__ x,
                                                  unsigned short* __restrict__ xb,
                                                  const int* __restrict__ edges,
                                                  int* __restrict__ g_hist) {
    __shared__ int hist[NCB];
    int t = threadIdx.x;
    if (blockIdx.x < CVT_BLOCKS) {
        int i = blockIdx.x * 256 + t;
        if (i >= MPAD * FDIM / 4) return;
        int base = i * 4;
        uint2 o;
        if (base < N_NODES * FDIM) {
            float4 v = *(const float4*)&x[base];
            o.x = (u32)f2bf(v.x) | ((u32)f2bf(v.y) << 16);
            o.y = (u32)f2bf(v.z) | ((u32)f2bf(v.w) << 16);
        } else { o.x = 0u; o.y = 0u; }
        *(uint2*)&xb[base] = o;
    } else {
        int blk = blockIdx.x - CVT_BLOCKS;
        if (t < NCB) hist[t] = 0;
        __syncthreads();
        int beg = blk * EPB, end = beg + EPB;
        for (int i = beg + t; i < end; i += 256) {
            int2 ed = ((const int2*)edges)[i];
            atomicAdd(&hist[ed.y >> 8], 1);
        }
        __syncthreads();
        if (t < NCB) g_hist[blk * NCB + t] = hist[t];   // [b][t]: scan reads coalesced
    }
}

// ---------------- scan: per-(bucket,block) local bases + bucket bases ----------------
__global__ __launch_bounds__(256) void scan_kernel(const int* __restrict__ g_hist,
                                                   int* __restrict__ g_base,
                                                   int* __restrict__ cbbase,
                                                   int* __restrict__ cbtotal,
                                                   int* __restrict__ row_ptr) {
    __shared__ int tot[NCB];
    int t = threadIdx.x;
    if (t < NCB) {
        int run = 0;
        for (int b = 0; b < ABLK; ++b) {          // coalesced over t each iter
            int v = g_hist[b * NCB + t];
            g_base[b * NCB + t] = run;
            run += v;
        }
        tot[t] = run;
    }
    __syncthreads();
    if (t == 0) {
        int run = 0;
        for (int c = 0; c < NCB; ++c) { cbbase[c] = run; cbtotal[c] = tot[c]; run += tot[c]; }
        row_ptr[N_NODES] = N_EDGES;
    }
}

// ---------------- A2: deterministic scatter into coarse buckets ----------------
__global__ __launch_bounds__(256) void scatter_kernel(const int* __restrict__ edges,
                                                      const int* __restrict__ g_base,
                                                      const int* __restrict__ cbbase,
                                                      u32* __restrict__ coarse) {
    __shared__ int cur[NCB];
    int t = threadIdx.x, blk = blockIdx.x;
    if (t < NCB) cur[t] = g_base[blk * NCB + t] + cbbase[t];
    __syncthreads();
    int beg = blk * EPB, end = beg + EPB;
    for (int i = beg + t; i < end; i += 256) {
        int2 ed = ((const int2*)edges)[i];   // x=src, y=dst
        int cb = ed.y >> 8;
        int pos = atomicAdd(&cur[cb], 1);
        coarse[pos] = ((u32)(ed.y & 255) << 16) | (u32)ed.x;
    }
}

// ---------------- B: per-coarse-bucket LDS counting sort -> csr_src/row_ptr/invdeg ----
__global__ __launch_bounds__(256) void csr_kernel(const int* __restrict__ cbbase,
                                                  const int* __restrict__ cbtotal,
                                                  const u32* __restrict__ coarse,
                                                  int* __restrict__ csr_src,
                                                  int* __restrict__ row_ptr,
                                                  float* __restrict__ invdeg) {
    __shared__ int cnt_l[CBN];
    __shared__ int off_l[CBN];
    int cb = blockIdx.x, t = threadIdx.x;
    int n = cbtotal[cb], base = cbbase[cb];
    cnt_l[t] = 0;
    __syncthreads();
    const u32* ce = coarse + base;
    for (int i = t; i < n; i += 256) atomicAdd(&cnt_l[ce[i] >> 16], 1);
    __syncthreads();
    if (t == 0) {
        int run = base;
        for (int i = 0; i < CBN; ++i) { off_l[i] = run; run += cnt_l[i]; }
    }
    __syncthreads();
    int node0 = cb * CBN;
    if (node0 + t < N_NODES) {
        row_ptr[node0 + t] = off_l[t];
        invdeg[node0 + t] = 1.0f / (float)max(cnt_l[t], 1);
    }
    __syncthreads();   // row_ptr snapshot before cursors move
    for (int i = t; i < n; i += 256) {
        u32 ev = ce[i];
        int pos = atomicAdd(&off_l[ev >> 16], 1);
        csr_src[pos] = (int)(ev & 0xFFFFu);
    }
}

// -------- weights -> bf16 transposed+concat; also zero gsum + per-graph invcnt --------
struct WPtrs { const float* wl[5]; const float* wr[5]; };
__global__ void convert_w_kernel(WPtrs wp, unsigned short* __restrict__ wcat,
                                 const int* __restrict__ batch,
                                 float* __restrict__ gsum,
                                 float* __restrict__ invcnt) {
    int t = blockIdx.x * blockDim.x + threadIdx.x;   // 5*128*256 = 163840
    if (t < NGRAPH * FDIM) gsum[t] = 0.0f;           // fold gsum zeroing
    if (t < NGRAPH) {                                // fold per-graph 1/count
        int g = t;
        int lo = 0, hi = N_NODES;
        while (lo < hi) { int mid = (lo + hi) >> 1; if (batch[mid] < g) lo = mid + 1; else hi = mid; }
        int beg = lo;
        hi = N_NODES;
        while (lo < hi) { int mid = (lo + hi) >> 1; if (batch[mid] < g + 1) lo = mid + 1; else hi = mid; }
        invcnt[g] = 1.0f / (float)max(lo - beg, 1);
    }
    if (t >= 5 * 128 * 256) return;
    int l = t >> 15;
    int rem = t & 32767;
    int k = rem >> 7;        // 0..255
    int n = rem & 127;       // coalesced read over n
    const float* W = (k < 128) ? wp.wl[l] : wp.wr[l];
    float v = W[(k & 127) * 128 + n];
    wcat[((size_t)l << 15) + n * 256 + k] = f2bf(v);
}

// ---------------- fused SAGE layer: gather agg tile into LDS, then MFMA ----------------
// 512 thr (8 waves), 64 rows/block. Gather at its measured latency wall
// (~62 us/layer — invariant to 2x waves [R9], 1/2 bytes [R10], 2x ILP [R11];
// edge-balanced restructure regressed 2x [R14]: per-CU miss-queue saturation
// x cross-XCD fabric latency is the floor). R9 gather kept verbatim.
// pool_batch != nullptr (layer 5): skip h-out store; stage relu tile in LDS,
// in-block sorted-batch reduction, ~2 atomics/feature/block into gsum.
__global__ __launch_bounds__(512) void sage_fused_kernel(
        const unsigned short* __restrict__ h,    // [MPAD][128] bf16
        const int* __restrict__ row_ptr,
        const int* __restrict__ csr_src,
        const float* __restrict__ invdeg,
        const unsigned short* __restrict__ Wcat, // [128 n][256 k] bf16
        const float* __restrict__ bias,
        unsigned short* __restrict__ out,
        const int* __restrict__ pool_batch,      // null for layers 1-4
        float* __restrict__ gsum) {
    __shared__ unsigned short As[64][136];
    int t = threadIdx.x;
    int node0 = blockIdx.x * 64;

    // ---- phase 1: gather (32 node-slots x 16 lanes, 2 sub-batches) ----
    {
        int slot = t >> 4;       // 0..31
        int lane = t & 15;
        int c = lane * 8;
        #pragma unroll
        for (int sb = 0; sb < 2; ++sb) {
            int nl = sb * 32 + slot;
            int node = node0 + nl;
            float acc[8] = {0.f, 0.f, 0.f, 0.f, 0.f, 0.f, 0.f, 0.f};
            if (node < N_NODES) {
                int beg = row_ptr[node], end = row_ptr[node + 1];
                int e = beg;
                for (; e + 4 <= end; e += 4) {
                    int s0 = csr_src[e + 0];
                    int s1 = csr_src[e + 1];
                    int s2 = csr_src[e + 2];
                    int s3 = csr_src[e + 3];
                    uint4 v0 = *(const uint4*)&h[(size_t)s0 * FDIM + c];
                    uint4 v1 = *(const uint4*)&h[(size_t)s1 * FDIM + c];
                    uint4 v2 = *(const uint4*)&h[(size_t)s2 * FDIM + c];
                    uint4 v3 = *(const uint4*)&h[(size_t)s3 * FDIM + c];
                    acc[0] += bflo(v0.x) + bflo(v1.x) + bflo(v2.x) + bflo(v3.x);
                    acc[1] += bfhi(v0.x) + bfhi(v1.x) + bfhi(v2.x) + bfhi(v3.x);
                    acc[2] += bflo(v0.y) + bflo(v1.y) + bflo(v2.y) + bflo(v3.y);
                    acc[3] += bfhi(v0.y) + bfhi(v1.y) + bfhi(v2.y) + bfhi(v3.y);
                    acc[4] += bflo(v0.z) + bflo(v1.z) + bflo(v2.z) + bflo(v3.z);
                    acc[5] += bfhi(v0.z) + bfhi(v1.z) + bfhi(v2.z) + bfhi(v3.z);
                    acc[6] += bflo(v0.w) + bflo(v1.w) + bflo(v2.w) + bflo(v3.w);
                    acc[7] += bfhi(v0.w) + bfhi(v1.w) + bfhi(v2.w) + bfhi(v3.w);
                }
                for (; e < end; ++e) {
                    int s = csr_src[e];
                    uint4 v = *(const uint4*)&h[(size_t)s * FDIM + c];
                    acc[0] += bflo(v.x); acc[1] += bfhi(v.x);
                    acc[2] += bflo(v.y); acc[3] += bfhi(v.y);
                    acc[4] += bflo(v.z); acc[5] += bfhi(v.z);
                    acc[6] += bflo(v.w); acc[7] += bfhi(v.w);
                }
                float inv = invdeg[node];
                #pragma unroll
                for (int i = 0; i < 8; ++i) acc[i] *= inv;
            }
            uint4 o;
            o.x = (u32)f2bf(acc[0]) | ((u32)f2bf(acc[1]) << 16);
            o.y = (u32)f2bf(acc[2]) | ((u32)f2bf(acc[3]) << 16);
            o.z = (u32)f2bf(acc[4]) | ((u32)f2bf(acc[5]) << 16);
            o.w = (u32)f2bf(acc[6]) | ((u32)f2bf(acc[7]) << 16);
            *(uint4*)&As[nl][c] = o;
        }
    }
    __syncthreads();

    // ---- phase 2: MFMA (8 waves; pair (stripe,half) covers 16 rows x 64 cols) ----
    int wave = t >> 6;
    int lane = t & 63;
    int l15 = lane & 15;
    int q = lane >> 4;
    int stripe = wave >> 1;              // 0..3 -> 16-row stripe
    int half = wave & 1;                 // 0..1 -> col-blocks half*4 .. half*4+3
    int row_base = node0 + stripe * 16;

    f32x4 acc[4];
    #pragma unroll
    for (int i = 0; i < 4; ++i) acc[i] = (f32x4){0.f, 0.f, 0.f, 0.f};

    // p=0: A = agg tile (LDS), Wl (k<128)
    {
        const unsigned short* Wb = Wcat + (size_t)(half * 64 + l15) * 256 + q * 8;
        #pragma unroll
        for (int k0 = 0; k0 < 128; k0 += 32) {
            short8 a = *(const short8*)&As[stripe * 16 + l15][q * 8 + k0];
            #pragma unroll
            for (int j = 0; j < 4; ++j) {
                short8 b = *(const short8*)(Wb + (size_t)j * 16 * 256 + k0);
                acc[j] = __builtin_amdgcn_mfma_f32_16x16x32_bf16(a, b, acc[j], 0, 0, 0);
            }
        }
    }
    // p=1: A = h (global bf16), Wr (k>=128)
    {
        const unsigned short* Ab = h + (size_t)(row_base + l15) * FDIM + q * 8;
        const unsigned short* Wb = Wcat + (size_t)(half * 64 + l15) * 256 + 128 + q * 8;
        #pragma unroll
        for (int k0 = 0; k0 < 128; k0 += 32) {
            short8 a = *(const short8*)(Ab + k0);
            #pragma unroll
            for (int j = 0; j < 4; ++j) {
                short8 b = *(const short8*)(Wb + (size_t)j * 16 * 256 + k0);
                acc[j] = __builtin_amdgcn_mfma_f32_16x16x32_bf16(a, b, acc[j], 0, 0, 0);
            }
        }
    }

    if (pool_batch == nullptr) {
        // epilogue: bias + relu + bf16 store
        #pragma unroll
        for (int j = 0; j < 4; ++j) {
            int col = (half * 4 + j) * 16 + l15;
            float bv = bias[col];
            #pragma unroll
            for (int r = 0; r < 4; ++r) {
                int row = row_base + q * 4 + r;
                float v = fmaxf(acc[j][r] + bv, 0.f);
                out[(size_t)row * FDIM + col] = f2bf(v);
            }
        }
    } else {
        // layer-5 epilogue: stage relu tile in LDS (bf16 -> identical numerics
        // to the old store+pool path), then in-block sorted-batch reduction.
        __syncthreads();                 // all waves done READING As (p=0)
        #pragma unroll
        for (int j = 0; j < 4; ++j) {
            int col = (half * 4 + j) * 16 + l15;
            float bv = bias[col];
            #pragma unroll
            for (int r = 0; r < 4; ++r) {
                int rl = stripe * 16 + q * 4 + r;
                As[rl][col] = f2bf(fmaxf(acc[j][r] + bv, 0.f));
            }
        }
        __syncthreads();
        if (t < FDIM) {
            int f = t;
            int nmax = min(64, N_NODES - node0);
            float a = 0.0f;
            int cur = pool_batch[node0];
            for (int r = 0; r < nmax; ++r) {
                int b = pool_batch[node0 + r];     // broadcast read
                if (b != cur) {
                    atomicAdd(&gsum[cur * FDIM + f], a);
                    a = 0.0f;
                    cur = b;
                }
                a += bflo((u32)As[r][f]);
            }
            atomicAdd(&gsum[cur * FDIM + f], a);
        }
    }
}

// ---------------- final MLP head (fp32): sigmoid(relu((gsum/cnt)@Wf1+bf1)@Wf2+bf2) -------
__global__ void mlp_kernel(const float* __restrict__ gsum,
                           const float* __restrict__ invcnt,
                           const float* __restrict__ Wf1, const float* __restrict__ bf1,
                           const float* __restrict__ Wf2, const float* __restrict__ bf2,
                           float* __restrict__ out) {
    int gg = blockIdx.x;
    int j = threadIdx.x;   // 128
    __shared__ float row[128];
    __shared__ float red[128];
    row[j] = gsum[gg * 128 + j] * invcnt[gg];
    __syncthreads();
    float acc = bf1[j];
    for (int k = 0; k < 128; ++k) acc = fmaf(row[k], Wf1[k * 128 + j], acc);
    float v = fmaxf(acc, 0.0f);
    red[j] = v * Wf2[j];
    __syncthreads();
    for (int off = 64; off > 0; off >>= 1) {
        if (j < off) red[j] += red[j + off];
        __syncthreads();
    }
    if (j == 0) out[gg] = 1.0f / (1.0f + expf(-(red[0] + bf2[0])));
}

extern "C" void kernel_launch(void* const* d_in, const int* in_sizes, int n_in,
                              void* d_out, int out_size, void* d_ws, size_t ws_size,
                              hipStream_t stream) {
    const float* x      = (const float*)d_in[0];
    const int*   edges  = (const int*)d_in[1];
    const int*   batch  = (const int*)d_in[2];
    WPtrs wp;
    const float* bs[5];
    for (int l = 0; l < 5; ++l) {
        wp.wl[l] = (const float*)d_in[3 + 3 * l];
        wp.wr[l] = (const float*)d_in[4 + 3 * l];
        bs[l]    = (const float*)d_in[5 + 3 * l];
    }
    const float* Wf1 = (const float*)d_in[18];
    const float* bf1 = (const float*)d_in[19];
    const float* Wf2 = (const float*)d_in[20];
    const float* bf2 = (const float*)d_in[21];
    float* out = (float*)d_out;

    // workspace carve-up (256B aligned)
    char* ws = (char*)d_ws;
    auto alloc = [&](size_t bytes) { void* p = (void*)ws; ws += (bytes + 255) & ~(size_t)255; return p; };
    unsigned short* xb   = (unsigned short*)alloc((size_t)MPAD * FDIM * 2);
    unsigned short* hA   = (unsigned short*)alloc((size_t)MPAD * FDIM * 2);
    unsigned short* hB   = (unsigned short*)alloc((size_t)MPAD * FDIM * 2);
    unsigned short* wcat = (unsigned short*)alloc((size_t)5 * 128 * 256 * 2);
    u32*   coarse   = (u32*)alloc((size_t)N_EDGES * 4);
    int*   g_hist   = (int*)alloc((size_t)NCB * ABLK * 4);
    int*   g_base   = (int*)alloc((size_t)NCB * ABLK * 4);
    int*   cbbase   = (int*)alloc((size_t)NCB * 4);
    int*   cbtotal  = (int*)alloc((size_t)NCB * 4);
    int*   row_ptr  = (int*)alloc((size_t)(N_NODES + 1) * 4);
    int*   csr_src  = (int*)alloc((size_t)N_EDGES * 4);
    float* invdeg   = (float*)alloc((size_t)N_NODES * 4);
    float* gsum     = (float*)alloc((size_t)NGRAPH * FDIM * 4);
    float* invcnt   = (float*)alloc((size_t)NGRAPH * 4);
    (void)ws_size; (void)in_sizes; (void)n_in; (void)out_size;

    // ---- conversions + CSR build (deterministic multi-split) ----
    pre_kernel<<<CVT_BLOCKS + ABLK, 256, 0, stream>>>(x, xb, edges, g_hist);
    convert_w_kernel<<<(5 * 128 * 256 + 255) / 256, 256, 0, stream>>>(wp, wcat, batch, gsum, invcnt);
    scan_kernel<<<1, 256, 0, stream>>>(g_hist, g_base, cbbase, cbtotal, row_ptr);
    scatter_kernel<<<ABLK, 256, 0, stream>>>(edges, g_base, cbbase, coarse);
    csr_kernel<<<NCB, 256, 0, stream>>>(cbbase, cbtotal, coarse, csr_src, row_ptr, invdeg);

    // ---- 5 fused SAGE layers; layer 5 folds the graph mean-pool ----
    const unsigned short* hcur = xb;
    unsigned short* bufs[2] = {hA, hB};
    for (int l = 0; l < 5; ++l) {
        unsigned short* hnext = bufs[l & 1];
        const int* pb = (l == 4) ? batch : nullptr;
        sage_fused_kernel<<<MPAD / 64, 512, 0, stream>>>(
            hcur, row_ptr, csr_src, invdeg, wcat + ((size_t)l << 15), bs[l], hnext, pb, gsum);
        hcur = hnext;
    }

    // ---- head ----
    mlp_kernel<<<NGRAPH, 128, 0, stream>>>(gsum, invcnt, Wf1, bf1, Wf2, bf2, out);
}